// Round 8
// baseline (164.927 us; speedup 1.0000x reference)
//
#include <hip/hip_runtime.h>
#include <hip/hip_bf16.h>
#include <cstdint>

#define D_MODEL 1024
#define SEQ     2048
#define SCALE   0.125f
#define P_ELEMS 2228224   // per-batch packed triangular elems: 16384*136

typedef __attribute__((ext_vector_type(8))) _Float16 f16x8;
typedef __attribute__((ext_vector_type(8))) unsigned short u16x8;
typedef __attribute__((ext_vector_type(4))) unsigned short u16x4;
typedef __attribute__((ext_vector_type(4))) float f32x4;

__device__ __forceinline__ unsigned short f2h(float f) {
  _Float16 h = (_Float16)f;
  return __builtin_bit_cast(unsigned short, h);
}

__device__ __forceinline__ void gll16(const void* g, void* lds_p) {
  __builtin_amdgcn_global_load_lds(
      (const __attribute__((address_space(1))) unsigned int*)(uintptr_t)g,
      (__attribute__((address_space(3))) unsigned int*)(unsigned int)(uintptr_t)lds_p,
      16, 0, 0);
}

#define WAITV8 asm volatile("s_waitcnt vmcnt(8)" ::: "memory")
#define WAITV0 asm volatile("s_waitcnt vmcnt(0)" ::: "memory")
#define WAITL0 asm volatile("s_waitcnt lgkmcnt(0)" ::: "memory")
#define SCHEDB __builtin_amdgcn_sched_barrier(0)
#define BAR    __builtin_amdgcn_s_barrier()

#define MFMA16(a, b, c) __builtin_amdgcn_mfma_f32_16x16x32_f16(a, b, c, 0, 0, 0)

// ============ 128-tile pipeline (4 waves) — used by qk_scores / pv_gemm ============
__device__ __forceinline__ void stage_tile(const unsigned short* gA, const unsigned short* gB,
                                           size_t sA, size_t sB,
                                           int k0, unsigned short* buf, int w, int lane) {
  int rl = lane >> 3;
  int sg = ((lane & 7) ^ rl) << 3;
#pragma unroll
  for (int j = 0; j < 4; j++) {
    int c = w * 4 + j;
    int row = c * 8 + rl;
    gll16(gA + (size_t)row * sA + k0 + sg, buf + c * 512);
    gll16(gB + (size_t)row * sB + k0 + sg, buf + 8192 + c * 512);
  }
}

__device__ __forceinline__ void load_frags(const unsigned short* buf, int wr, int wc,
                                           int l15, int l4, f16x8 af[4][2], f16x8 bf[4][2]) {
  const unsigned short* bA = buf;
  const unsigned short* bB = buf + 8192;
#pragma unroll
  for (int m = 0; m < 4; m++) {
    int row = wr * 64 + m * 16 + l15, rs = row & 7;
    af[m][0] = *(const f16x8*)(bA + row * 64 + ((l4 ^ rs) << 3));
    af[m][1] = *(const f16x8*)(bA + row * 64 + (((4 + l4) ^ rs) << 3));
  }
#pragma unroll
  for (int n = 0; n < 4; n++) {
    int row = wc * 64 + n * 16 + l15, rs = row & 7;
    bf[n][0] = *(const f16x8*)(bB + row * 64 + ((l4 ^ rs) << 3));
    bf[n][1] = *(const f16x8*)(bB + row * 64 + (((4 + l4) ^ rs) << 3));
  }
}

__device__ __forceinline__ void mfma_tile(f16x8 af[4][2], f16x8 bf[4][2], f32x4 acc[4][4]) {
#pragma unroll
  for (int m = 0; m < 4; m++)
#pragma unroll
    for (int n = 0; n < 4; n++) {
      acc[m][n] = MFMA16(af[m][0], bf[n][0], acc[m][n]);
      acc[m][n] = MFMA16(af[m][1], bf[n][1], acc[m][n]);
    }
}

__device__ __forceinline__ void gemm_core(const unsigned short* gA, const unsigned short* gB,
                                          size_t sA, size_t sB,
                                          unsigned short* lds0, unsigned short* lds1, int nt,
                                          int w, int lane, int wr, int wc, int l15, int l4,
                                          f32x4 acc[4][4]) {
  stage_tile(gA, gB, sA, sB, 0, lds0, w, lane);
  stage_tile(gA, gB, sA, sB, 64, lds1, w, lane);
  WAITV8; SCHEDB; BAR;
  f16x8 af[4][2], bf[4][2];
  for (int t = 0; t < nt; t += 2) {
    load_frags(lds0, wr, wc, l15, l4, af, bf);
    WAITL0; SCHEDB; BAR;
    if (t + 2 < nt) stage_tile(gA, gB, sA, sB, (t + 2) * 64, lds0, w, lane);
    __builtin_amdgcn_s_setprio(1);
    mfma_tile(af, bf, acc);
    __builtin_amdgcn_s_setprio(0);
    if (t + 2 < nt) { WAITV8; } else { WAITV0; }
    SCHEDB; BAR;
    load_frags(lds1, wr, wc, l15, l4, af, bf);
    WAITL0; SCHEDB; BAR;
    if (t + 3 < nt) stage_tile(gA, gB, sA, sB, (t + 3) * 64, lds1, w, lane);
    __builtin_amdgcn_s_setprio(1);
    mfma_tile(af, bf, acc);
    __builtin_amdgcn_s_setprio(0);
    if (t + 3 < nt) { WAITV8; } else { WAITV0; }
    SCHEDB; BAR;
  }
}

// ============ 256-tile pipeline (8 waves, wave-tile 128x64) — qkv ============
// A[256][64] + B[256][64] per K-tile; 8 gll/thread/tile; vmcnt(8) steady state.
__device__ __forceinline__ void stage_tile256(const unsigned short* gA, const unsigned short* gB,
                                              size_t sA, size_t sB, int k0,
                                              unsigned short* buf, int w, int lane) {
  int rl = lane >> 3;
  int sg = ((lane & 7) ^ rl) << 3;
#pragma unroll
  for (int j = 0; j < 4; j++) {
    int c = w * 4 + j;                 // 0..31
    int row = c * 8 + rl;              // 0..255
    gll16(gA + (size_t)row * sA + k0 + sg, buf + c * 512);
    gll16(gB + (size_t)row * sB + k0 + sg, buf + 16384 + c * 512);
  }
}

__device__ __forceinline__ void gemm_core256(const unsigned short* gA, const unsigned short* gB,
                                             size_t sA, size_t sB,
                                             unsigned short* lds0, unsigned short* lds1, int nt,
                                             int w, int lane, int wr, int wc, int l15, int l4,
                                             f32x4 acc[8][4]) {
  stage_tile256(gA, gB, sA, sB, 0, lds0, w, lane);
  stage_tile256(gA, gB, sA, sB, 64, lds1, w, lane);
  WAITV8; SCHEDB; BAR;
  for (int t = 0; t < nt; t++) {
    unsigned short* buf = (t & 1) ? lds1 : lds0;
    const unsigned short* bA = buf;
    const unsigned short* bB = buf + 16384;
    f16x8 bf[4][2], af[4][2], ag[4][2];
#pragma unroll
    for (int n = 0; n < 4; n++) {
      int row = wc * 64 + n * 16 + l15, rs = row & 7;
      bf[n][0] = *(const f16x8*)(bB + row * 64 + ((l4 ^ rs) << 3));
      bf[n][1] = *(const f16x8*)(bB + row * 64 + (((4 + l4) ^ rs) << 3));
    }
#pragma unroll
    for (int m = 0; m < 4; m++) {
      int row = wr * 128 + m * 16 + l15, rs = row & 7;
      af[m][0] = *(const f16x8*)(bA + row * 64 + ((l4 ^ rs) << 3));
      af[m][1] = *(const f16x8*)(bA + row * 64 + (((4 + l4) ^ rs) << 3));
    }
    // MFMA lower half (m0-3) — register-only, overlaps upper-half ds_reads
#pragma unroll
    for (int m = 0; m < 4; m++)
#pragma unroll
      for (int n = 0; n < 4; n++) {
        acc[m][n] = MFMA16(af[m][0], bf[n][0], acc[m][n]);
        acc[m][n] = MFMA16(af[m][1], bf[n][1], acc[m][n]);
      }
#pragma unroll
    for (int m = 0; m < 4; m++) {
      int row = wr * 128 + 64 + m * 16 + l15, rs = row & 7;
      ag[m][0] = *(const f16x8*)(bA + row * 64 + ((l4 ^ rs) << 3));
      ag[m][1] = *(const f16x8*)(bA + row * 64 + (((4 + l4) ^ rs) << 3));
    }
    WAITL0; SCHEDB; BAR;                 // all waves done reading buf
    if (t + 2 < nt) stage_tile256(gA, gB, sA, sB, (t + 2) * 64, buf, w, lane);
    __builtin_amdgcn_s_setprio(1);
#pragma unroll
    for (int m = 0; m < 4; m++)
#pragma unroll
      for (int n = 0; n < 4; n++) {
        acc[m + 4][n] = MFMA16(ag[m][0], bf[n][0], acc[m + 4][n]);
        acc[m + 4][n] = MFMA16(ag[m][1], bf[n][1], acc[m + 4][n]);
      }
    __builtin_amdgcn_s_setprio(0);
    if (t + 2 < nt) { WAITV8; } else { WAITV0; }
    SCHEDB; BAR;
  }
}

// ---- kernel 1: fused converts. blocks 0..4095: x f32->f16; 4096..7167: W transpose ----
__global__ __launch_bounds__(256) void cvt_fused(const float* __restrict__ x,
                                                 const float* __restrict__ W0,
                                                 const float* __restrict__ W1,
                                                 const float* __restrict__ W2,
                                                 unsigned short* __restrict__ xb,
                                                 unsigned short* __restrict__ wt) {
  __shared__ float t[32][33];
  int bid = blockIdx.x;
  int tid = threadIdx.x;
  if (bid < 4096) {
    int i = bid * 256 + tid;
    const float4* p = (const float4*)x + (size_t)i * 2;
    float4 a = p[0], b = p[1];
    u16x8 r;
    r[0] = f2h(a.x); r[1] = f2h(a.y); r[2] = f2h(a.z); r[3] = f2h(a.w);
    r[4] = f2h(b.x); r[5] = f2h(b.y); r[6] = f2h(b.z); r[7] = f2h(b.w);
    *((u16x8*)xb + i) = r;
  } else {
    int id = bid - 4096;              // 0..3071
    int z = id >> 10, rem = id & 1023;
    int bx = rem & 31, by = rem >> 5;
    const float* W = (z == 0) ? W0 : (z == 1 ? W1 : W2);
    unsigned short* o = wt + (size_t)z * 1048576;
    int c0 = bx * 32, r0 = by * 32;
    int tx = tid & 31, ty = tid >> 5;
    for (int i = 0; i < 4; i++)
      t[ty + 8 * i][tx] = W[(size_t)(r0 + ty + 8 * i) * 1024 + c0 + tx];
    __syncthreads();
    for (int i = 0; i < 4; i++)
      o[(size_t)(c0 + ty + 8 * i) * 1024 + r0 + tx] = f2h(t[tx][ty + 8 * i]);
  }
}

// ---- kernel 2: fused QKV GEMM, 256x256 tile, 8 waves; V written transposed ----
__global__ __launch_bounds__(512, 2) void qkv_gemm(const unsigned short* __restrict__ xb,
                                                   const unsigned short* __restrict__ wt,
                                                   const float* __restrict__ b0,
                                                   const float* __restrict__ b1,
                                                   const float* __restrict__ b2,
                                                   unsigned short* __restrict__ Qp,
                                                   unsigned short* __restrict__ Kp,
                                                   unsigned short* __restrict__ vtp) {
  __shared__ unsigned short lds[2][32768];   // [buf][A 16384 | B 16384]
  int m0 = blockIdx.x * 256;
  int n0 = blockIdx.y * 256;
  int z = n0 >> 10, nz = n0 & 1023;
  const unsigned short* gA = xb + (size_t)m0 * 1024;
  const unsigned short* gB = wt + (size_t)z * 1048576 + (size_t)nz * 1024;
  const float* bias = (z == 0) ? b0 : (z == 1 ? b1 : b2);
  int tid = threadIdx.x, lane = tid & 63, w = tid >> 6;
  int wr = w >> 2, wc = w & 3, l15 = lane & 15, l4 = lane >> 4;
  f32x4 acc[8][4] = {};
  gemm_core256(gA, gB, 1024, 1024, &lds[0][0], &lds[1][0], 16, w, lane, wr, wc, l15, l4, acc);

  if (z < 2) {
    unsigned short* O = (z == 0) ? Qp : Kp;
#pragma unroll
    for (int m = 0; m < 8; m++)
#pragma unroll
      for (int n = 0; n < 4; n++) {
        int cl = wc * 64 + n * 16 + l15;
        float bv = bias[nz + cl];
#pragma unroll
        for (int r = 0; r < 4; r++) {
          int row = m0 + wr * 128 + m * 16 + l4 * 4 + r;
          O[(size_t)row * 1024 + nz + cl] = f2h(acc[m][n][r] + bv);
        }
      }
  } else {
    // V: two-pass LDS transpose (s-half h), T[d 0..255][s 0..127] stride 136
    unsigned short* T = &lds[0][0];          // 256*136 = 34816 ushorts (fits 65536)
    int bidx = m0 >> 11, s0 = m0 & 2047;
#pragma unroll
    for (int h = 0; h < 2; h++) {
      __syncthreads();
      if (wr == h) {
#pragma unroll
        for (int m = 0; m < 8; m++)
#pragma unroll
          for (int n = 0; n < 4; n++) {
            int cl = wc * 64 + n * 16 + l15;
            float bv = bias[nz + cl];
#pragma unroll
            for (int r = 0; r < 4; r++) {
              int rl = m * 16 + l4 * 4 + r;      // 0..127
              T[cl * 136 + rl] = f2h(acc[m][n][r] + bv);
            }
          }
      }
      __syncthreads();
#pragma unroll
      for (int i = 0; i < 8; i++) {
        int idx = i * 512 + tid;
        int d = idx >> 4, ch = idx & 15;
        u16x8 v = *(const u16x8*)(T + d * 136 + ch * 8);
        *(u16x8*)(vtp + ((size_t)bidx * 1024 + nz + d) * 2048 + s0 + h * 128 + ch * 8) = v;
      }
    }
  }
}

// ---- kernel 3: scores = Q K^T * SCALE, causal mask, triangular-packed f32 ----
__global__ __launch_bounds__(256) void qk_scores(const unsigned short* __restrict__ Q,
                                                 const unsigned short* __restrict__ Kb,
                                                 float* __restrict__ sc) {
  __shared__ unsigned short lds[2][16384];
  int b = blockIdx.y;
  int i = blockIdx.x;
  int qt = (int)((sqrtf(8.f * i + 1.f) - 1.f) * 0.5f);
  while ((qt + 1) * (qt + 2) / 2 <= i) qt++;
  while (qt * (qt + 1) / 2 > i) qt--;
  int kt = i - qt * (qt + 1) / 2;
  int Wspan = (qt + 1) << 7;
  const unsigned short* gA = Q  + ((size_t)b * 2048 + qt * 128) * 1024;
  const unsigned short* gB = Kb + ((size_t)b * 2048 + kt * 128) * 1024;
  float* outp = sc + (size_t)b * P_ELEMS + (size_t)16384 * (qt * (qt + 1) / 2);
  int tid = threadIdx.x, lane = tid & 63, w = tid >> 6;
  int wr = w >> 1, wc = w & 1, l15 = lane & 15, l4 = lane >> 4;
  f32x4 acc[4][4] = {};
  gemm_core(gA, gB, 1024, 1024, &lds[0][0], &lds[1][0], 16, w, lane, wr, wc, l15, l4, acc);
#pragma unroll
  for (int m = 0; m < 4; m++)
#pragma unroll
    for (int n = 0; n < 4; n++) {
      int cl = wc * 64 + n * 16 + l15;
      int kv = kt * 128 + cl;
#pragma unroll
      for (int r = 0; r < 4; r++) {
        int rl = wr * 64 + m * 16 + l4 * 4 + r;
        int srow = qt * 128 + rl;
        float v = acc[m][n][r] * SCALE;
        if (kv > srow) v = -1e30f;
        outp[(size_t)rl * Wspan + kv] = v;
      }
    }
}

// ---- kernel 4: row softmax (row in registers), write f16 P packed ----
__global__ __launch_bounds__(256) void softmax_row(const float* __restrict__ sc,
                                                   unsigned short* __restrict__ pb) {
  __shared__ float redm[4];
  __shared__ float reds[4];
  int srow = blockIdx.x;
  int b = srow >> 11, sl = srow & 2047;
  int qt = sl >> 7;
  int Wspan = (qt + 1) << 7;
  size_t rb = (size_t)b * P_ELEMS + (size_t)16384 * (qt * (qt + 1) / 2) + (size_t)(sl & 127) * Wspan;
  const float4* src = (const float4*)(sc + rb);
  int nv = Wspan >> 2;
  int t = threadIdx.x, lane = t & 63, w = t >> 6;
  bool h0 = t < nv, h1 = (t + 256) < nv;
  float4 v0 = make_float4(0, 0, 0, 0), v1 = make_float4(0, 0, 0, 0);
  if (h0) v0 = src[t];
  if (h1) v1 = src[t + 256];
  float mx = -1e30f;
  if (h0) mx = fmaxf(fmaxf(v0.x, v0.y), fmaxf(v0.z, v0.w));
  if (h1) mx = fmaxf(mx, fmaxf(fmaxf(v1.x, v1.y), fmaxf(v1.z, v1.w)));
  for (int off = 1; off < 64; off <<= 1) mx = fmaxf(mx, __shfl_xor(mx, off, 64));
  if (lane == 0) redm[w] = mx;
  __syncthreads();
  mx = fmaxf(fmaxf(redm[0], redm[1]), fmaxf(redm[2], redm[3]));
  float s = 0.f;
  float4 e0, e1;
  if (h0) {
    e0.x = __expf(v0.x - mx); e0.y = __expf(v0.y - mx);
    e0.z = __expf(v0.z - mx); e0.w = __expf(v0.w - mx);
    s += e0.x + e0.y + e0.z + e0.w;
  }
  if (h1) {
    e1.x = __expf(v1.x - mx); e1.y = __expf(v1.y - mx);
    e1.z = __expf(v1.z - mx); e1.w = __expf(v1.w - mx);
    s += e1.x + e1.y + e1.z + e1.w;
  }
  for (int off = 1; off < 64; off <<= 1) s += __shfl_xor(s, off, 64);
  if (lane == 0) reds[w] = s;
  __syncthreads();
  s = reds[0] + reds[1] + reds[2] + reds[3];
  float inv = 1.f / s;
  u16x4* dst = (u16x4*)(pb + rb);
  if (h0) {
    u16x4 o;
    o[0] = f2h(e0.x * inv); o[1] = f2h(e0.y * inv);
    o[2] = f2h(e0.z * inv); o[3] = f2h(e0.w * inv);
    dst[t] = o;
  }
  if (h1) {
    u16x4 o;
    o[0] = f2h(e1.x * inv); o[1] = f2h(e1.y * inv);
    o[2] = f2h(e1.z * inv); o[3] = f2h(e1.w * inv);
    dst[t + 256] = o;
  }
}

// ---- kernel 5: O = P Vt — paired tiles (qt=p and 15-p): 34 K-iters per block ----
__global__ __launch_bounds__(256) void pv_gemm(const unsigned short* __restrict__ pb,
                                               const unsigned short* __restrict__ vtp,
                                               float* __restrict__ outp) {
  __shared__ unsigned short lds[2][16384];
  int p = blockIdx.x;        // 0..7
  int n0 = blockIdx.y * 128;
  int b = blockIdx.z;
  int tid = threadIdx.x, lane = tid & 63, w = tid >> 6;
  int wr = w >> 1, wc = w & 1, l15 = lane & 15, l4 = lane >> 4;
  const unsigned short* gB = vtp + (size_t)b * 1024 * 2048 + (size_t)n0 * 2048;
#pragma unroll
  for (int which = 0; which < 2; which++) {
    int qt = which ? (15 - p) : p;
    int Wspan = (qt + 1) << 7;
    const unsigned short* gA = pb + (size_t)b * P_ELEMS + (size_t)16384 * (qt * (qt + 1) / 2);
    float* O = outp + ((size_t)b * 2048 + qt * 128) * 1024;
    f32x4 acc[4][4] = {};
    gemm_core(gA, gB, Wspan, 2048, &lds[0][0], &lds[1][0], 2 * (qt + 1),
              w, lane, wr, wc, l15, l4, acc);
#pragma unroll
    for (int m = 0; m < 4; m++)
#pragma unroll
      for (int n = 0; n < 4; n++) {
        int cl = n0 + wc * 64 + n * 16 + l15;
#pragma unroll
        for (int r = 0; r < 4; r++) {
          int rl = wr * 64 + m * 16 + l4 * 4 + r;
          O[(size_t)rl * 1024 + cl] = acc[m][n][r];
        }
      }
  }
}

extern "C" void kernel_launch(void* const* d_in, const int* in_sizes, int n_in,
                              void* d_out, int out_size, void* d_ws, size_t ws_size,
                              hipStream_t stream) {
  const float* x  = (const float*)d_in[0];
  const float* Wq = (const float*)d_in[1];
  const float* bq = (const float*)d_in[2];
  const float* Wk = (const float*)d_in[3];
  const float* bk = (const float*)d_in[4];
  const float* Wv = (const float*)d_in[5];
  const float* bv = (const float*)d_in[6];
  float* out = (float*)d_out;

  unsigned short* ws  = (unsigned short*)d_ws;
  unsigned short* wt  = ws;                          // 3,145,728 ushorts
  unsigned short* Qp  = ws + 3145728;                // 8,388,608
  unsigned short* Kp  = ws + 11534336;               // 8,388,608
  unsigned short* vtp = ws + 19922944;               // 8,388,608 (V^T [b][d][s])
  float* sc           = (float*)(ws + 28311552);     // 4*P_ELEMS f32 (packed tri)
  unsigned short* pb  = ws + 46137344;               // 4*P_ELEMS f16 (packed tri)
  unsigned short* xb  = (unsigned short*)d_out;      // x f16 scratch (overwritten by pv)

  cvt_fused<<<7168, 256, 0, stream>>>(x, Wq, Wk, Wv, xb, wt);
  qkv_gemm<<<dim3(32, 12), 512, 0, stream>>>(xb, wt, bq, bk, bv, Qp, Kp, vtp);
  qk_scores<<<dim3(136, 4), 256, 0, stream>>>(Qp, Kp, sc);
  softmax_row<<<8192, 256, 0, stream>>>(sc, pb);
  pv_gemm<<<dim3(8, 8, 4), 256, 0, stream>>>(pb, vtp, out);
}

// Round 9
// 157.744 us; speedup vs baseline: 1.0455x; 1.0455x over previous
//
#include <hip/hip_runtime.h>
#include <hip/hip_bf16.h>
#include <cstdint>

#define D_MODEL 1024
#define SEQ     2048
#define SCALE   0.125f
#define P_ELEMS 2228224   // per-batch packed triangular elems: 16384*136

typedef __attribute__((ext_vector_type(8))) _Float16 f16x8;
typedef __attribute__((ext_vector_type(8))) unsigned short u16x8;
typedef __attribute__((ext_vector_type(4))) float f32x4;

__device__ __forceinline__ unsigned short f2h(float f) {
  _Float16 h = (_Float16)f;
  return __builtin_bit_cast(unsigned short, h);
}
__device__ __forceinline__ float h2f(unsigned short u) {
  return (float)__builtin_bit_cast(_Float16, u);
}

__device__ __forceinline__ void gll16(const void* g, void* lds_p) {
  __builtin_amdgcn_global_load_lds(
      (const __attribute__((address_space(1))) unsigned int*)(uintptr_t)g,
      (__attribute__((address_space(3))) unsigned int*)(unsigned int)(uintptr_t)lds_p,
      16, 0, 0);
}

#define WAITV8 asm volatile("s_waitcnt vmcnt(8)" ::: "memory")
#define WAITV0 asm volatile("s_waitcnt vmcnt(0)" ::: "memory")
#define WAITL0 asm volatile("s_waitcnt lgkmcnt(0)" ::: "memory")
#define SCHEDB __builtin_amdgcn_sched_barrier(0)
#define BAR    __builtin_amdgcn_s_barrier()
#define MFMA16(a, b, c) __builtin_amdgcn_mfma_f32_16x16x32_f16(a, b, c, 0, 0, 0)

// ============ 128-tile pipeline (4 waves) ============
__device__ __forceinline__ void stage_tile(const unsigned short* gA, const unsigned short* gB,
                                           size_t sA, size_t sB,
                                           int k0, unsigned short* buf, int w, int lane) {
  int rl = lane >> 3;
  int sg = ((lane & 7) ^ rl) << 3;
#pragma unroll
  for (int j = 0; j < 4; j++) {
    int c = w * 4 + j;
    int row = c * 8 + rl;
    gll16(gA + (size_t)row * sA + k0 + sg, buf + c * 512);
    gll16(gB + (size_t)row * sB + k0 + sg, buf + 8192 + c * 512);
  }
}

__device__ __forceinline__ void load_frags(const unsigned short* buf, int wr, int wc,
                                           int l15, int l4, f16x8 af[4][2], f16x8 bf[4][2]) {
  const unsigned short* bA = buf;
  const unsigned short* bB = buf + 8192;
#pragma unroll
  for (int m = 0; m < 4; m++) {
    int row = wr * 64 + m * 16 + l15, rs = row & 7;
    af[m][0] = *(const f16x8*)(bA + row * 64 + ((l4 ^ rs) << 3));
    af[m][1] = *(const f16x8*)(bA + row * 64 + (((4 + l4) ^ rs) << 3));
  }
#pragma unroll
  for (int n = 0; n < 4; n++) {
    int row = wc * 64 + n * 16 + l15, rs = row & 7;
    bf[n][0] = *(const f16x8*)(bB + row * 64 + ((l4 ^ rs) << 3));
    bf[n][1] = *(const f16x8*)(bB + row * 64 + (((4 + l4) ^ rs) << 3));
  }
}

__device__ __forceinline__ void mfma_tile(f16x8 af[4][2], f16x8 bf[4][2], f32x4 acc[4][4]) {
#pragma unroll
  for (int m = 0; m < 4; m++)
#pragma unroll
    for (int n = 0; n < 4; n++) {
      acc[m][n] = MFMA16(af[m][0], bf[n][0], acc[m][n]);
      acc[m][n] = MFMA16(af[m][1], bf[n][1], acc[m][n]);
    }
}

__device__ __forceinline__ void gemm_core(const unsigned short* gA, const unsigned short* gB,
                                          size_t sA, size_t sB,
                                          unsigned short* lds0, unsigned short* lds1, int nt,
                                          int w, int lane, int wr, int wc, int l15, int l4,
                                          f32x4 acc[4][4]) {
  stage_tile(gA, gB, sA, sB, 0, lds0, w, lane);
  stage_tile(gA, gB, sA, sB, 64, lds1, w, lane);
  WAITV8; SCHEDB; BAR;
  f16x8 af[4][2], bf[4][2];
  for (int t = 0; t < nt; t += 2) {
    load_frags(lds0, wr, wc, l15, l4, af, bf);
    WAITL0; SCHEDB; BAR;
    if (t + 2 < nt) stage_tile(gA, gB, sA, sB, (t + 2) * 64, lds0, w, lane);
    __builtin_amdgcn_s_setprio(1);
    mfma_tile(af, bf, acc);
    __builtin_amdgcn_s_setprio(0);
    if (t + 2 < nt) { WAITV8; } else { WAITV0; }
    SCHEDB; BAR;
    load_frags(lds1, wr, wc, l15, l4, af, bf);
    WAITL0; SCHEDB; BAR;
    if (t + 3 < nt) stage_tile(gA, gB, sA, sB, (t + 3) * 64, lds1, w, lane);
    __builtin_amdgcn_s_setprio(1);
    mfma_tile(af, bf, acc);
    __builtin_amdgcn_s_setprio(0);
    if (t + 3 < nt) { WAITV8; } else { WAITV0; }
    SCHEDB; BAR;
  }
}

// ---- kernel 1: fused converts. blocks 0..4095: x f32->f16; 4096..7167: W transpose ----
__global__ __launch_bounds__(256) void cvt_fused(const float* __restrict__ x,
                                                 const float* __restrict__ W0,
                                                 const float* __restrict__ W1,
                                                 const float* __restrict__ W2,
                                                 unsigned short* __restrict__ xb,
                                                 unsigned short* __restrict__ wt) {
  __shared__ float t[32][33];
  int bid = blockIdx.x;
  int tid = threadIdx.x;
  if (bid < 4096) {
    int i = bid * 256 + tid;
    const float4* p = (const float4*)x + (size_t)i * 2;
    float4 a = p[0], b = p[1];
    u16x8 r;
    r[0] = f2h(a.x); r[1] = f2h(a.y); r[2] = f2h(a.z); r[3] = f2h(a.w);
    r[4] = f2h(b.x); r[5] = f2h(b.y); r[6] = f2h(b.z); r[7] = f2h(b.w);
    *((u16x8*)xb + i) = r;
  } else {
    int id = bid - 4096;              // 0..3071
    int z = id >> 10, rem = id & 1023;
    int bx = rem & 31, by = rem >> 5;
    const float* W = (z == 0) ? W0 : (z == 1 ? W1 : W2);
    unsigned short* o = wt + (size_t)z * 1048576;
    int c0 = bx * 32, r0 = by * 32;
    int tx = tid & 31, ty = tid >> 5;
    for (int i = 0; i < 4; i++)
      t[ty + 8 * i][tx] = W[(size_t)(r0 + ty + 8 * i) * 1024 + c0 + tx];
    __syncthreads();
    for (int i = 0; i < 4; i++)
      o[(size_t)(c0 + ty + 8 * i) * 1024 + r0 + tx] = f2h(t[tx][ty + 8 * i]);
  }
}

// ---- kernel 2: fused QKV GEMM (r7 128-tile structure + XCD swizzle) ----
__global__ __launch_bounds__(256) void qkv_gemm(const unsigned short* __restrict__ xb,
                                                const unsigned short* __restrict__ wt,
                                                const float* __restrict__ b0,
                                                const float* __restrict__ b1,
                                                const float* __restrict__ b2,
                                                unsigned short* __restrict__ Qp,
                                                unsigned short* __restrict__ Kp,
                                                unsigned short* __restrict__ vtp) {
  __shared__ unsigned short lds[2][16384];   // [buf][A 8192 | B 8192]
  // XCD-aware bijective swizzle: 1536 blocks, 8 XCDs, 192/XCD
  int lin = blockIdx.y * 64 + blockIdx.x;
  int swz = (lin & 7) * 192 + (lin >> 3);
  int m0 = (swz & 63) * 128;
  int n0 = (swz >> 6) * 128;
  int z = n0 >> 10, nz = n0 & 1023;
  const unsigned short* gA = xb + (size_t)m0 * 1024;
  const unsigned short* gB = wt + (size_t)z * 1048576 + (size_t)nz * 1024;
  const float* bias = (z == 0) ? b0 : (z == 1 ? b1 : b2);
  int tid = threadIdx.x, lane = tid & 63, w = tid >> 6;
  int wr = w >> 1, wc = w & 1, l15 = lane & 15, l4 = lane >> 4;
  f32x4 acc[4][4] = {};
  gemm_core(gA, gB, 1024, 1024, &lds[0][0], &lds[1][0], 16, w, lane, wr, wc, l15, l4, acc);

  if (z < 2) {
    unsigned short* O = (z == 0) ? Qp : Kp;
#pragma unroll
    for (int m = 0; m < 4; m++)
#pragma unroll
      for (int n = 0; n < 4; n++) {
        int cl = wc * 64 + n * 16 + l15;
        float bv = bias[nz + cl];
#pragma unroll
        for (int r = 0; r < 4; r++) {
          int row = m0 + wr * 64 + m * 16 + l4 * 4 + r;
          O[(size_t)row * 1024 + nz + cl] = f2h(acc[m][n][r] + bv);
        }
      }
  } else {
    // V: transpose 128x128 tile in LDS, then coalesced store to vtp[b][d][s]
    unsigned short* T = &lds[0][0];          // 128 x 136 f16
#pragma unroll
    for (int m = 0; m < 4; m++)
#pragma unroll
      for (int n = 0; n < 4; n++) {
        int cl = wc * 64 + n * 16 + l15;     // d-local
        float bv = bias[nz + cl];
#pragma unroll
        for (int r = 0; r < 4; r++) {
          int rl = wr * 64 + m * 16 + l4 * 4 + r;   // s-local
          T[cl * 136 + rl] = f2h(acc[m][n][r] + bv);
        }
      }
    __syncthreads();
    int bidx = m0 >> 11, s0 = m0 & 2047;
#pragma unroll
    for (int i = 0; i < 8; i++) {
      int d = w * 32 + i * 4 + (lane >> 4);
      int ch = lane & 15;
      u16x8 v = *(const u16x8*)(T + d * 136 + ch * 8);
      *(u16x8*)(vtp + ((size_t)bidx * 1024 + nz + d) * 2048 + s0 + ch * 8) = v;
    }
  }
}

// ---- kernel 3: scores = Q K^T * SCALE, causal mask, triangular-packed **f16** ----
__global__ __launch_bounds__(256) void qk_scores(const unsigned short* __restrict__ Q,
                                                 const unsigned short* __restrict__ Kb,
                                                 unsigned short* __restrict__ sc) {
  __shared__ unsigned short lds[2][16384];
  // XCD swizzle over 544 blocks (544 % 8 == 0 -> bijective)
  int lin = blockIdx.y * 136 + blockIdx.x;
  int swz = (lin & 7) * 68 + (lin >> 3);
  int i = swz % 136;
  int b = swz / 136;
  int qt = (int)((sqrtf(8.f * i + 1.f) - 1.f) * 0.5f);
  while ((qt + 1) * (qt + 2) / 2 <= i) qt++;
  while (qt * (qt + 1) / 2 > i) qt--;
  int kt = i - qt * (qt + 1) / 2;
  int Wspan = (qt + 1) << 7;
  const unsigned short* gA = Q  + ((size_t)b * 2048 + qt * 128) * 1024;
  const unsigned short* gB = Kb + ((size_t)b * 2048 + kt * 128) * 1024;
  unsigned short* outp = sc + (size_t)b * P_ELEMS + (size_t)16384 * (qt * (qt + 1) / 2);
  int tid = threadIdx.x, lane = tid & 63, w = tid >> 6;
  int wr = w >> 1, wc = w & 1, l15 = lane & 15, l4 = lane >> 4;
  f32x4 acc[4][4] = {};
  gemm_core(gA, gB, 1024, 1024, &lds[0][0], &lds[1][0], 16, w, lane, wr, wc, l15, l4, acc);
#pragma unroll
  for (int m = 0; m < 4; m++)
#pragma unroll
    for (int n = 0; n < 4; n++) {
      int cl = wc * 64 + n * 16 + l15;
      int kv = kt * 128 + cl;
#pragma unroll
      for (int r = 0; r < 4; r++) {
        int rl = wr * 64 + m * 16 + l4 * 4 + r;
        int srow = qt * 128 + rl;
        float v = acc[m][n][r] * SCALE;
        if (kv > srow) v = -30000.f;      // f16-representable; exp -> 0
        outp[(size_t)rl * Wspan + kv] = f2h(v);
      }
    }
}

// ---- kernel 4: row softmax over f16 scores (8 elems/thread), write f16 P ----
__global__ __launch_bounds__(256) void softmax_row(const unsigned short* __restrict__ sc,
                                                   unsigned short* __restrict__ pb) {
  __shared__ float redm[4];
  __shared__ float reds[4];
  int srow = blockIdx.x;
  int b = srow >> 11, sl = srow & 2047;
  int qt = sl >> 7;
  int Wspan = (qt + 1) << 7;
  size_t rb = (size_t)b * P_ELEMS + (size_t)16384 * (qt * (qt + 1) / 2) + (size_t)(sl & 127) * Wspan;
  const u16x8* src = (const u16x8*)(sc + rb);
  int nv = Wspan >> 3;                       // <= 256
  int t = threadIdx.x, lane = t & 63, w = t >> 6;
  bool h0 = t < nv;
  float v[8];
  float mx = -1e30f;
  if (h0) {
    u16x8 raw = src[t];
#pragma unroll
    for (int j = 0; j < 8; j++) { v[j] = h2f(raw[j]); mx = fmaxf(mx, v[j]); }
  }
  for (int off = 1; off < 64; off <<= 1) mx = fmaxf(mx, __shfl_xor(mx, off, 64));
  if (lane == 0) redm[w] = mx;
  __syncthreads();
  mx = fmaxf(fmaxf(redm[0], redm[1]), fmaxf(redm[2], redm[3]));
  float s = 0.f;
  if (h0) {
#pragma unroll
    for (int j = 0; j < 8; j++) { v[j] = __expf(v[j] - mx); s += v[j]; }
  }
  for (int off = 1; off < 64; off <<= 1) s += __shfl_xor(s, off, 64);
  if (lane == 0) reds[w] = s;
  __syncthreads();
  s = reds[0] + reds[1] + reds[2] + reds[3];
  float inv = 1.f / s;
  if (h0) {
    u16x8 o;
#pragma unroll
    for (int j = 0; j < 8; j++) o[j] = f2h(v[j] * inv);
    *((u16x8*)(pb + rb) + t) = o;
  }
}

// ---- kernel 5: O = P Vt — paired tiles (qt=p and 15-p): 34 K-iters per block ----
__global__ __launch_bounds__(256) void pv_gemm(const unsigned short* __restrict__ pb,
                                               const unsigned short* __restrict__ vtp,
                                               float* __restrict__ outp) {
  __shared__ unsigned short lds[2][16384];
  int p = blockIdx.x;        // 0..7
  int n0 = blockIdx.y * 128;
  int b = blockIdx.z;
  int tid = threadIdx.x, lane = tid & 63, w = tid >> 6;
  int wr = w >> 1, wc = w & 1, l15 = lane & 15, l4 = lane >> 4;
  const unsigned short* gB = vtp + (size_t)b * 1024 * 2048 + (size_t)n0 * 2048;
#pragma unroll
  for (int which = 0; which < 2; which++) {
    int qt = which ? (15 - p) : p;
    int Wspan = (qt + 1) << 7;
    const unsigned short* gA = pb + (size_t)b * P_ELEMS + (size_t)16384 * (qt * (qt + 1) / 2);
    float* O = outp + ((size_t)b * 2048 + qt * 128) * 1024;
    f32x4 acc[4][4] = {};
    gemm_core(gA, gB, Wspan, 2048, &lds[0][0], &lds[1][0], 2 * (qt + 1),
              w, lane, wr, wc, l15, l4, acc);
#pragma unroll
    for (int m = 0; m < 4; m++)
#pragma unroll
      for (int n = 0; n < 4; n++) {
        int cl = n0 + wc * 64 + n * 16 + l15;
#pragma unroll
        for (int r = 0; r < 4; r++) {
          int rl = wr * 64 + m * 16 + l4 * 4 + r;
          O[(size_t)rl * 1024 + cl] = acc[m][n][r];
        }
      }
  }
}

extern "C" void kernel_launch(void* const* d_in, const int* in_sizes, int n_in,
                              void* d_out, int out_size, void* d_ws, size_t ws_size,
                              hipStream_t stream) {
  const float* x  = (const float*)d_in[0];
  const float* Wq = (const float*)d_in[1];
  const float* bq = (const float*)d_in[2];
  const float* Wk = (const float*)d_in[3];
  const float* bk = (const float*)d_in[4];
  const float* Wv = (const float*)d_in[5];
  const float* bv = (const float*)d_in[6];
  float* out = (float*)d_out;

  unsigned short* ws  = (unsigned short*)d_ws;
  unsigned short* wt  = ws;                          // 3,145,728 ushorts
  unsigned short* Qp  = ws + 3145728;                // 8,388,608
  unsigned short* Kp  = ws + 11534336;               // 8,388,608
  unsigned short* vtp = ws + 19922944;               // 8,388,608 (V^T [b][d][s])
  unsigned short* sc  = ws + 28311552;               // 4*P_ELEMS f16 scores
  unsigned short* pb  = ws + 37224448;               // 4*P_ELEMS f16 P
  unsigned short* xb  = (unsigned short*)d_out;      // x f16 scratch (overwritten by pv)

  cvt_fused<<<7168, 256, 0, stream>>>(x, Wq, Wk, Wv, xb, wt);
  qkv_gemm<<<dim3(64, 24), 256, 0, stream>>>(xb, wt, bq, bk, bv, Qp, Kp, vtp);
  qk_scores<<<dim3(136, 4), 256, 0, stream>>>(Qp, Kp, sc);
  softmax_row<<<8192, 256, 0, stream>>>(sc, pb);
  pv_gemm<<<dim3(8, 8, 4), 256, 0, stream>>>(pb, vtp, out);
}

// Round 10
// 156.128 us; speedup vs baseline: 1.0564x; 1.0104x over previous
//
#include <hip/hip_runtime.h>
#include <hip/hip_bf16.h>
#include <cstdint>

#define D_MODEL 1024
#define SEQ     2048
#define SCALE   0.125f
#define P_ELEMS 2228224   // per-batch packed triangular elems: 16384*136

typedef __attribute__((ext_vector_type(8))) _Float16 f16x8;
typedef __attribute__((ext_vector_type(8))) unsigned short u16x8;
typedef __attribute__((ext_vector_type(4))) float f32x4;

__device__ __forceinline__ unsigned short f2h(float f) {
  _Float16 h = (_Float16)f;
  return __builtin_bit_cast(unsigned short, h);
}
__device__ __forceinline__ float h2f(unsigned short u) {
  return (float)__builtin_bit_cast(_Float16, u);
}

__device__ __forceinline__ void gll16(const void* g, void* lds_p) {
  __builtin_amdgcn_global_load_lds(
      (const __attribute__((address_space(1))) unsigned int*)(uintptr_t)g,
      (__attribute__((address_space(3))) unsigned int*)(unsigned int)(uintptr_t)lds_p,
      16, 0, 0);
}

#define WAITV8 asm volatile("s_waitcnt vmcnt(8)" ::: "memory")
#define WAITV0 asm volatile("s_waitcnt vmcnt(0)" ::: "memory")
#define WAITL0 asm volatile("s_waitcnt lgkmcnt(0)" ::: "memory")
#define SCHEDB __builtin_amdgcn_sched_barrier(0)
#define BAR    __builtin_amdgcn_s_barrier()
#define MFMA16(a, b, c) __builtin_amdgcn_mfma_f32_16x16x32_f16(a, b, c, 0, 0, 0)

// ============ 128-tile pipeline (4 waves) ============
__device__ __forceinline__ void stage_tile(const unsigned short* gA, const unsigned short* gB,
                                           size_t sA, size_t sB,
                                           int k0, unsigned short* buf, int w, int lane) {
  int rl = lane >> 3;
  int sg = ((lane & 7) ^ rl) << 3;
#pragma unroll
  for (int j = 0; j < 4; j++) {
    int c = w * 4 + j;
    int row = c * 8 + rl;
    gll16(gA + (size_t)row * sA + k0 + sg, buf + c * 512);
    gll16(gB + (size_t)row * sB + k0 + sg, buf + 8192 + c * 512);
  }
}

__device__ __forceinline__ void load_frags(const unsigned short* buf, int wr, int wc,
                                           int l15, int l4, f16x8 af[4][2], f16x8 bf[4][2]) {
  const unsigned short* bA = buf;
  const unsigned short* bB = buf + 8192;
#pragma unroll
  for (int m = 0; m < 4; m++) {
    int row = wr * 64 + m * 16 + l15, rs = row & 7;
    af[m][0] = *(const f16x8*)(bA + row * 64 + ((l4 ^ rs) << 3));
    af[m][1] = *(const f16x8*)(bA + row * 64 + (((4 + l4) ^ rs) << 3));
  }
#pragma unroll
  for (int n = 0; n < 4; n++) {
    int row = wc * 64 + n * 16 + l15, rs = row & 7;
    bf[n][0] = *(const f16x8*)(bB + row * 64 + ((l4 ^ rs) << 3));
    bf[n][1] = *(const f16x8*)(bB + row * 64 + (((4 + l4) ^ rs) << 3));
  }
}

__device__ __forceinline__ void mfma_tile(f16x8 af[4][2], f16x8 bf[4][2], f32x4 acc[4][4]) {
#pragma unroll
  for (int m = 0; m < 4; m++)
#pragma unroll
    for (int n = 0; n < 4; n++) {
      acc[m][n] = MFMA16(af[m][0], bf[n][0], acc[m][n]);
      acc[m][n] = MFMA16(af[m][1], bf[n][1], acc[m][n]);
    }
}

__device__ __forceinline__ void gemm_core(const unsigned short* gA, const unsigned short* gB,
                                          size_t sA, size_t sB,
                                          unsigned short* lds0, unsigned short* lds1, int nt,
                                          int w, int lane, int wr, int wc, int l15, int l4,
                                          f32x4 acc[4][4]) {
  stage_tile(gA, gB, sA, sB, 0, lds0, w, lane);
  stage_tile(gA, gB, sA, sB, 64, lds1, w, lane);
  WAITV8; SCHEDB; BAR;
  f16x8 af[4][2], bf[4][2];
  for (int t = 0; t < nt; t += 2) {
    load_frags(lds0, wr, wc, l15, l4, af, bf);
    WAITL0; SCHEDB; BAR;
    if (t + 2 < nt) stage_tile(gA, gB, sA, sB, (t + 2) * 64, lds0, w, lane);
    __builtin_amdgcn_s_setprio(1);
    mfma_tile(af, bf, acc);
    __builtin_amdgcn_s_setprio(0);
    if (t + 2 < nt) { WAITV8; } else { WAITV0; }
    SCHEDB; BAR;
    load_frags(lds1, wr, wc, l15, l4, af, bf);
    WAITL0; SCHEDB; BAR;
    if (t + 3 < nt) stage_tile(gA, gB, sA, sB, (t + 3) * 64, lds1, w, lane);
    __builtin_amdgcn_s_setprio(1);
    mfma_tile(af, bf, acc);
    __builtin_amdgcn_s_setprio(0);
    if (t + 3 < nt) { WAITV0; }
    else if (t + 3 < nt + 1) { WAITV0; }
    SCHEDB; BAR;
  }
}

// ---- kernel 1: fused converts. blocks 0..4095: x f32->f16; 4096..7167: W transpose ----
__global__ __launch_bounds__(256) void cvt_fused(const float* __restrict__ x,
                                                 const float* __restrict__ W0,
                                                 const float* __restrict__ W1,
                                                 const float* __restrict__ W2,
                                                 unsigned short* __restrict__ xb,
                                                 unsigned short* __restrict__ wt) {
  __shared__ float t[32][33];
  int bid = blockIdx.x;
  int tid = threadIdx.x;
  if (bid < 4096) {
    int i = bid * 256 + tid;
    const float4* p = (const float4*)x + (size_t)i * 2;
    float4 a = p[0], b = p[1];
    u16x8 r;
    r[0] = f2h(a.x); r[1] = f2h(a.y); r[2] = f2h(a.z); r[3] = f2h(a.w);
    r[4] = f2h(b.x); r[5] = f2h(b.y); r[6] = f2h(b.z); r[7] = f2h(b.w);
    *((u16x8*)xb + i) = r;
  } else {
    int id = bid - 4096;              // 0..3071
    int z = id >> 10, rem = id & 1023;
    int bx = rem & 31, by = rem >> 5;
    const float* W = (z == 0) ? W0 : (z == 1 ? W1 : W2);
    unsigned short* o = wt + (size_t)z * 1048576;
    int c0 = bx * 32, r0 = by * 32;
    int tx = tid & 31, ty = tid >> 5;
    for (int i = 0; i < 4; i++)
      t[ty + 8 * i][tx] = W[(size_t)(r0 + ty + 8 * i) * 1024 + c0 + tx];
    __syncthreads();
    for (int i = 0; i < 4; i++)
      o[(size_t)(c0 + ty + 8 * i) * 1024 + r0 + tx] = f2h(t[tx][ty + 8 * i]);
  }
}

// ---- kernel 2: fused QKV GEMM (r7 structure, natural block mapping) ----
__global__ __launch_bounds__(256) void qkv_gemm(const unsigned short* __restrict__ xb,
                                                const unsigned short* __restrict__ wt,
                                                const float* __restrict__ b0,
                                                const float* __restrict__ b1,
                                                const float* __restrict__ b2,
                                                unsigned short* __restrict__ Qp,
                                                unsigned short* __restrict__ Kp,
                                                unsigned short* __restrict__ vtp) {
  __shared__ unsigned short lds[2][16384];   // [buf][A 8192 | B 8192]
  int m0 = blockIdx.x * 128;
  int n0 = blockIdx.y * 128;
  int z = n0 >> 10, nz = n0 & 1023;
  const unsigned short* gA = xb + (size_t)m0 * 1024;
  const unsigned short* gB = wt + (size_t)z * 1048576 + (size_t)nz * 1024;
  const float* bias = (z == 0) ? b0 : (z == 1 ? b1 : b2);
  int tid = threadIdx.x, lane = tid & 63, w = tid >> 6;
  int wr = w >> 1, wc = w & 1, l15 = lane & 15, l4 = lane >> 4;
  f32x4 acc[4][4] = {};
  gemm_core(gA, gB, 1024, 1024, &lds[0][0], &lds[1][0], 16, w, lane, wr, wc, l15, l4, acc);

  if (z < 2) {
    unsigned short* O = (z == 0) ? Qp : Kp;
#pragma unroll
    for (int m = 0; m < 4; m++)
#pragma unroll
      for (int n = 0; n < 4; n++) {
        int cl = wc * 64 + n * 16 + l15;
        float bv = bias[nz + cl];
#pragma unroll
        for (int r = 0; r < 4; r++) {
          int row = m0 + wr * 64 + m * 16 + l4 * 4 + r;
          O[(size_t)row * 1024 + nz + cl] = f2h(acc[m][n][r] + bv);
        }
      }
  } else {
    // V: transpose 128x128 tile in LDS, then coalesced store to vtp[b][d][s]
    unsigned short* T = &lds[0][0];          // 128 x 136 f16
#pragma unroll
    for (int m = 0; m < 4; m++)
#pragma unroll
      for (int n = 0; n < 4; n++) {
        int cl = wc * 64 + n * 16 + l15;     // d-local
        float bv = bias[nz + cl];
#pragma unroll
        for (int r = 0; r < 4; r++) {
          int rl = wr * 64 + m * 16 + l4 * 4 + r;   // s-local
          T[cl * 136 + rl] = f2h(acc[m][n][r] + bv);
        }
      }
    __syncthreads();
    int bidx = m0 >> 11, s0 = m0 & 2047;
#pragma unroll
    for (int i = 0; i < 8; i++) {
      int d = w * 32 + i * 4 + (lane >> 4);
      int ch = lane & 15;
      u16x8 v = *(const u16x8*)(T + d * 136 + ch * 8);
      *(u16x8*)(vtp + ((size_t)bidx * 1024 + nz + d) * 2048 + s0 + ch * 8) = v;
    }
  }
}

// ---- kernel 3: scores = Q K^T * SCALE, causal mask, triangular-packed f16 ----
__global__ __launch_bounds__(256) void qk_scores(const unsigned short* __restrict__ Q,
                                                 const unsigned short* __restrict__ Kb,
                                                 unsigned short* __restrict__ sc) {
  __shared__ unsigned short lds[2][16384];
  int b = blockIdx.y;
  int i = blockIdx.x;
  int qt = (int)((sqrtf(8.f * i + 1.f) - 1.f) * 0.5f);
  while ((qt + 1) * (qt + 2) / 2 <= i) qt++;
  while (qt * (qt + 1) / 2 > i) qt--;
  int kt = i - qt * (qt + 1) / 2;
  int Wspan = (qt + 1) << 7;
  const unsigned short* gA = Q  + ((size_t)b * 2048 + qt * 128) * 1024;
  const unsigned short* gB = Kb + ((size_t)b * 2048 + kt * 128) * 1024;
  unsigned short* outp = sc + (size_t)b * P_ELEMS + (size_t)16384 * (qt * (qt + 1) / 2);
  int tid = threadIdx.x, lane = tid & 63, w = tid >> 6;
  int wr = w >> 1, wc = w & 1, l15 = lane & 15, l4 = lane >> 4;
  f32x4 acc[4][4] = {};
  gemm_core(gA, gB, 1024, 1024, &lds[0][0], &lds[1][0], 16, w, lane, wr, wc, l15, l4, acc);
#pragma unroll
  for (int m = 0; m < 4; m++)
#pragma unroll
    for (int n = 0; n < 4; n++) {
      int cl = wc * 64 + n * 16 + l15;
      int kv = kt * 128 + cl;
#pragma unroll
      for (int r = 0; r < 4; r++) {
        int rl = wr * 64 + m * 16 + l4 * 4 + r;
        int srow = qt * 128 + rl;
        float v = acc[m][n][r] * SCALE;
        if (kv > srow) v = -30000.f;      // f16-representable; exp -> 0
        outp[(size_t)rl * Wspan + kv] = f2h(v);
      }
    }
}

// ---- kernel 4: row softmax over f16 scores (8 elems/thread), write f16 P ----
__global__ __launch_bounds__(256) void softmax_row(const unsigned short* __restrict__ sc,
                                                   unsigned short* __restrict__ pb) {
  __shared__ float redm[4];
  __shared__ float reds[4];
  int srow = blockIdx.x;
  int b = srow >> 11, sl = srow & 2047;
  int qt = sl >> 7;
  int Wspan = (qt + 1) << 7;
  size_t rb = (size_t)b * P_ELEMS + (size_t)16384 * (qt * (qt + 1) / 2) + (size_t)(sl & 127) * Wspan;
  const u16x8* src = (const u16x8*)(sc + rb);
  int nv = Wspan >> 3;                       // <= 256
  int t = threadIdx.x, lane = t & 63, w = t >> 6;
  bool h0 = t < nv;
  float v[8];
  float mx = -1e30f;
  if (h0) {
    u16x8 raw = src[t];
#pragma unroll
    for (int j = 0; j < 8; j++) { v[j] = h2f(raw[j]); mx = fmaxf(mx, v[j]); }
  }
  for (int off = 1; off < 64; off <<= 1) mx = fmaxf(mx, __shfl_xor(mx, off, 64));
  if (lane == 0) redm[w] = mx;
  __syncthreads();
  mx = fmaxf(fmaxf(redm[0], redm[1]), fmaxf(redm[2], redm[3]));
  float s = 0.f;
  if (h0) {
#pragma unroll
    for (int j = 0; j < 8; j++) { v[j] = __expf(v[j] - mx); s += v[j]; }
  }
  for (int off = 1; off < 64; off <<= 1) s += __shfl_xor(s, off, 64);
  if (lane == 0) reds[w] = s;
  __syncthreads();
  s = reds[0] + reds[1] + reds[2] + reds[3];
  float inv = 1.f / s;
  if (h0) {
    u16x8 o;
#pragma unroll
    for (int j = 0; j < 8; j++) o[j] = f2h(v[j] * inv);
    *((u16x8*)(pb + rb) + t) = o;
  }
}

// ---- kernel 5: O = P Vt — paired tiles (qt=p and 15-p): 34 K-iters per block ----
__global__ __launch_bounds__(256) void pv_gemm(const unsigned short* __restrict__ pb,
                                               const unsigned short* __restrict__ vtp,
                                               float* __restrict__ outp) {
  __shared__ unsigned short lds[2][16384];
  int p = blockIdx.x;        // 0..7
  int n0 = blockIdx.y * 128;
  int b = blockIdx.z;
  int tid = threadIdx.x, lane = tid & 63, w = tid >> 6;
  int wr = w >> 1, wc = w & 1, l15 = lane & 15, l4 = lane >> 4;
  const unsigned short* gB = vtp + (size_t)b * 1024 * 2048 + (size_t)n0 * 2048;
#pragma unroll
  for (int which = 0; which < 2; which++) {
    int qt = which ? (15 - p) : p;
    int Wspan = (qt + 1) << 7;
    const unsigned short* gA = pb + (size_t)b * P_ELEMS + (size_t)16384 * (qt * (qt + 1) / 2);
    float* O = outp + ((size_t)b * 2048 + qt * 128) * 1024;
    f32x4 acc[4][4] = {};
    gemm_core(gA, gB, Wspan, 2048, &lds[0][0], &lds[1][0], 2 * (qt + 1),
              w, lane, wr, wc, l15, l4, acc);
#pragma unroll
    for (int m = 0; m < 4; m++)
#pragma unroll
      for (int n = 0; n < 4; n++) {
        int cl = n0 + wc * 64 + n * 16 + l15;
#pragma unroll
        for (int r = 0; r < 4; r++) {
          int rl = wr * 64 + m * 16 + l4 * 4 + r;
          O[(size_t)rl * 1024 + cl] = acc[m][n][r];
        }
      }
  }
}

extern "C" void kernel_launch(void* const* d_in, const int* in_sizes, int n_in,
                              void* d_out, int out_size, void* d_ws, size_t ws_size,
                              hipStream_t stream) {
  const float* x  = (const float*)d_in[0];
  const float* Wq = (const float*)d_in[1];
  const float* bq = (const float*)d_in[2];
  const float* Wk = (const float*)d_in[3];
  const float* bk = (const float*)d_in[4];
  const float* Wv = (const float*)d_in[5];
  const float* bv = (const float*)d_in[6];
  float* out = (float*)d_out;

  unsigned short* ws  = (unsigned short*)d_ws;
  unsigned short* wt  = ws;                          // 3,145,728 ushorts
  unsigned short* Qp  = ws + 3145728;                // 8,388,608
  unsigned short* Kp  = ws + 11534336;               // 8,388,608
  unsigned short* vtp = ws + 19922944;               // 8,388,608 (V^T [b][d][s])
  unsigned short* sc  = ws + 28311552;               // 4*P_ELEMS f16 scores
  unsigned short* pb  = ws + 37224448;               // 4*P_ELEMS f16 P
  unsigned short* xb  = (unsigned short*)d_out;      // x f16 scratch (overwritten by pv)

  cvt_fused<<<7168, 256, 0, stream>>>(x, Wq, Wk, Wv, xb, wt);
  qkv_gemm<<<dim3(64, 24), 256, 0, stream>>>(xb, wt, bq, bk, bv, Qp, Kp, vtp);
  qk_scores<<<dim3(136, 4), 256, 0, stream>>>(Qp, Kp, sc);
  softmax_row<<<8192, 256, 0, stream>>>(sc, pb);
  pv_gemm<<<dim3(8, 8, 4), 256, 0, stream>>>(pb, vtp, out);
}

// Round 11
// 155.304 us; speedup vs baseline: 1.0620x; 1.0053x over previous
//
#include <hip/hip_runtime.h>
#include <hip/hip_bf16.h>
#include <cstdint>

#define D_MODEL 1024
#define SEQ     2048
#define SCALE   0.125f
#define P_ELEMS 2228224   // per-batch packed triangular elems: 16384*136

typedef __attribute__((ext_vector_type(8))) _Float16 f16x8;
typedef __attribute__((ext_vector_type(8))) unsigned short u16x8;
typedef __attribute__((ext_vector_type(4))) float f32x4;

__device__ __forceinline__ unsigned short f2h(float f) {
  _Float16 h = (_Float16)f;
  return __builtin_bit_cast(unsigned short, h);
}
__device__ __forceinline__ float h2f(unsigned short u) {
  return (float)__builtin_bit_cast(_Float16, u);
}

__device__ __forceinline__ void gll16(const void* g, void* lds_p) {
  __builtin_amdgcn_global_load_lds(
      (const __attribute__((address_space(1))) unsigned int*)(uintptr_t)g,
      (__attribute__((address_space(3))) unsigned int*)(unsigned int)(uintptr_t)lds_p,
      16, 0, 0);
}

#define WAITV8 asm volatile("s_waitcnt vmcnt(8)" ::: "memory")
#define WAITV0 asm volatile("s_waitcnt vmcnt(0)" ::: "memory")
#define WAITL8 asm volatile("s_waitcnt lgkmcnt(8)" ::: "memory")
#define WAITL0 asm volatile("s_waitcnt lgkmcnt(0)" ::: "memory")
#define SCHEDB __builtin_amdgcn_sched_barrier(0)
#define BAR    __builtin_amdgcn_s_barrier()
#define MFMA16(a, b, c) __builtin_amdgcn_mfma_f32_16x16x32_f16(a, b, c, 0, 0, 0)

// ============ 128-tile pipeline (4 waves) ============
__device__ __forceinline__ void stage_tile(const unsigned short* gA, const unsigned short* gB,
                                           size_t sA, size_t sB,
                                           int k0, unsigned short* buf, int w, int lane) {
  int rl = lane >> 3;
  int sg = ((lane & 7) ^ rl) << 3;
#pragma unroll
  for (int j = 0; j < 4; j++) {
    int c = w * 4 + j;
    int row = c * 8 + rl;
    gll16(gA + (size_t)row * sA + k0 + sg, buf + c * 512);
    gll16(gB + (size_t)row * sB + k0 + sg, buf + 8192 + c * 512);
  }
}

// Deep-pipelined K-loop with intra-tile k-slice interleave:
//   reads(all) -> lgkm(8) -> MFMA slice0 (overlaps slice1 reads)
//   -> lgkm(0)+BAR -> stage t+2 -> MFMA slice1 (overlaps stage issue)
//   -> vmcnt(8) counted (t+1 landed, t+2 in flight) -> BAR
__device__ __forceinline__ void gemm_core(const unsigned short* gA, const unsigned short* gB,
                                          size_t sA, size_t sB,
                                          unsigned short* lds0, unsigned short* lds1, int nt,
                                          int w, int lane, int wr, int wc, int l15, int l4,
                                          f32x4 acc[4][4]) {
  stage_tile(gA, gB, sA, sB, 0, lds0, w, lane);
  stage_tile(gA, gB, sA, sB, 64, lds1, w, lane);
  WAITV8; SCHEDB; BAR;
  for (int t = 0; t < nt; t++) {
    const unsigned short* buf = (t & 1) ? lds1 : lds0;
    const unsigned short* bA = buf;
    const unsigned short* bB = buf + 8192;
    f16x8 a0[4], b0[4], a1[4], b1[4];
    // k-slice 0 reads (8 x b128)
#pragma unroll
    for (int m = 0; m < 4; m++) {
      int row = wr * 64 + m * 16 + l15, rs = row & 7;
      a0[m] = *(const f16x8*)(bA + row * 64 + ((l4 ^ rs) << 3));
    }
#pragma unroll
    for (int n = 0; n < 4; n++) {
      int row = wc * 64 + n * 16 + l15, rs = row & 7;
      b0[n] = *(const f16x8*)(bB + row * 64 + ((l4 ^ rs) << 3));
    }
    // k-slice 1 reads (8 x b128)
#pragma unroll
    for (int m = 0; m < 4; m++) {
      int row = wr * 64 + m * 16 + l15, rs = row & 7;
      a1[m] = *(const f16x8*)(bA + row * 64 + (((4 + l4) ^ rs) << 3));
    }
#pragma unroll
    for (int n = 0; n < 4; n++) {
      int row = wc * 64 + n * 16 + l15, rs = row & 7;
      b1[n] = *(const f16x8*)(bB + row * 64 + (((4 + l4) ^ rs) << 3));
    }
    WAITL8; SCHEDB;                 // slice-0 reads retired; slice-1 still in flight
    __builtin_amdgcn_s_setprio(1);
#pragma unroll
    for (int m = 0; m < 4; m++)
#pragma unroll
      for (int n = 0; n < 4; n++)
        acc[m][n] = MFMA16(a0[m], b0[n], acc[m][n]);
    __builtin_amdgcn_s_setprio(0);
    WAITL0; SCHEDB; BAR;            // ALL reads retired -> buf dead for this tile
    if (t + 2 < nt) stage_tile(gA, gB, sA, sB, (t + 2) * 64,
                               (unsigned short*)buf, w, lane);
    __builtin_amdgcn_s_setprio(1);
#pragma unroll
    for (int m = 0; m < 4; m++)
#pragma unroll
      for (int n = 0; n < 4; n++)
        acc[m][n] = MFMA16(a1[m], b1[n], acc[m][n]);
    __builtin_amdgcn_s_setprio(0);
    if (t + 2 < nt) { WAITV8; } else { WAITV0; }   // tile t+1 landed
    SCHEDB; BAR;
  }
}

// ---- kernel 1: fused converts. blocks 0..4095: x f32->f16; 4096..7167: W transpose ----
__global__ __launch_bounds__(256) void cvt_fused(const float* __restrict__ x,
                                                 const float* __restrict__ W0,
                                                 const float* __restrict__ W1,
                                                 const float* __restrict__ W2,
                                                 unsigned short* __restrict__ xb,
                                                 unsigned short* __restrict__ wt) {
  __shared__ float t[32][33];
  int bid = blockIdx.x;
  int tid = threadIdx.x;
  if (bid < 4096) {
    int i = bid * 256 + tid;
    const float4* p = (const float4*)x + (size_t)i * 2;
    float4 a = p[0], b = p[1];
    u16x8 r;
    r[0] = f2h(a.x); r[1] = f2h(a.y); r[2] = f2h(a.z); r[3] = f2h(a.w);
    r[4] = f2h(b.x); r[5] = f2h(b.y); r[6] = f2h(b.z); r[7] = f2h(b.w);
    *((u16x8*)xb + i) = r;
  } else {
    int id = bid - 4096;              // 0..3071
    int z = id >> 10, rem = id & 1023;
    int bx = rem & 31, by = rem >> 5;
    const float* W = (z == 0) ? W0 : (z == 1 ? W1 : W2);
    unsigned short* o = wt + (size_t)z * 1048576;
    int c0 = bx * 32, r0 = by * 32;
    int tx = tid & 31, ty = tid >> 5;
    for (int i = 0; i < 4; i++)
      t[ty + 8 * i][tx] = W[(size_t)(r0 + ty + 8 * i) * 1024 + c0 + tx];
    __syncthreads();
    for (int i = 0; i < 4; i++)
      o[(size_t)(c0 + ty + 8 * i) * 1024 + r0 + tx] = f2h(t[tx][ty + 8 * i]);
  }
}

// ---- kernel 2: fused QKV GEMM (natural block mapping) ----
__global__ __launch_bounds__(256) void qkv_gemm(const unsigned short* __restrict__ xb,
                                                const unsigned short* __restrict__ wt,
                                                const float* __restrict__ b0,
                                                const float* __restrict__ b1,
                                                const float* __restrict__ b2,
                                                unsigned short* __restrict__ Qp,
                                                unsigned short* __restrict__ Kp,
                                                unsigned short* __restrict__ vtp) {
  __shared__ unsigned short lds[2][16384];   // [buf][A 8192 | B 8192]
  int m0 = blockIdx.x * 128;
  int n0 = blockIdx.y * 128;
  int z = n0 >> 10, nz = n0 & 1023;
  const unsigned short* gA = xb + (size_t)m0 * 1024;
  const unsigned short* gB = wt + (size_t)z * 1048576 + (size_t)nz * 1024;
  const float* bias = (z == 0) ? b0 : (z == 1 ? b1 : b2);
  int tid = threadIdx.x, lane = tid & 63, w = tid >> 6;
  int wr = w >> 1, wc = w & 1, l15 = lane & 15, l4 = lane >> 4;
  f32x4 acc[4][4] = {};
  gemm_core(gA, gB, 1024, 1024, &lds[0][0], &lds[1][0], 16, w, lane, wr, wc, l15, l4, acc);

  if (z < 2) {
    unsigned short* O = (z == 0) ? Qp : Kp;
#pragma unroll
    for (int m = 0; m < 4; m++)
#pragma unroll
      for (int n = 0; n < 4; n++) {
        int cl = wc * 64 + n * 16 + l15;
        float bv = bias[nz + cl];
#pragma unroll
        for (int r = 0; r < 4; r++) {
          int row = m0 + wr * 64 + m * 16 + l4 * 4 + r;
          O[(size_t)row * 1024 + nz + cl] = f2h(acc[m][n][r] + bv);
        }
      }
  } else {
    // V: transpose 128x128 tile in LDS, then coalesced store to vtp[b][d][s]
    unsigned short* T = &lds[0][0];          // 128 x 136 f16
#pragma unroll
    for (int m = 0; m < 4; m++)
#pragma unroll
      for (int n = 0; n < 4; n++) {
        int cl = wc * 64 + n * 16 + l15;     // d-local
        float bv = bias[nz + cl];
#pragma unroll
        for (int r = 0; r < 4; r++) {
          int rl = wr * 64 + m * 16 + l4 * 4 + r;   // s-local
          T[cl * 136 + rl] = f2h(acc[m][n][r] + bv);
        }
      }
    __syncthreads();
    int bidx = m0 >> 11, s0 = m0 & 2047;
#pragma unroll
    for (int i = 0; i < 8; i++) {
      int d = w * 32 + i * 4 + (lane >> 4);
      int ch = lane & 15;
      u16x8 v = *(const u16x8*)(T + d * 136 + ch * 8);
      *(u16x8*)(vtp + ((size_t)bidx * 1024 + nz + d) * 2048 + s0 + ch * 8) = v;
    }
  }
}

// ---- kernel 3: scores = Q K^T * SCALE, causal mask, triangular-packed f16 ----
__global__ __launch_bounds__(256) void qk_scores(const unsigned short* __restrict__ Q,
                                                 const unsigned short* __restrict__ Kb,
                                                 unsigned short* __restrict__ sc) {
  __shared__ unsigned short lds[2][16384];
  int b = blockIdx.y;
  int i = blockIdx.x;
  int qt = (int)((sqrtf(8.f * i + 1.f) - 1.f) * 0.5f);
  while ((qt + 1) * (qt + 2) / 2 <= i) qt++;
  while (qt * (qt + 1) / 2 > i) qt--;
  int kt = i - qt * (qt + 1) / 2;
  int Wspan = (qt + 1) << 7;
  const unsigned short* gA = Q  + ((size_t)b * 2048 + qt * 128) * 1024;
  const unsigned short* gB = Kb + ((size_t)b * 2048 + kt * 128) * 1024;
  unsigned short* outp = sc + (size_t)b * P_ELEMS + (size_t)16384 * (qt * (qt + 1) / 2);
  int tid = threadIdx.x, lane = tid & 63, w = tid >> 6;
  int wr = w >> 1, wc = w & 1, l15 = lane & 15, l4 = lane >> 4;
  f32x4 acc[4][4] = {};
  gemm_core(gA, gB, 1024, 1024, &lds[0][0], &lds[1][0], 16, w, lane, wr, wc, l15, l4, acc);
#pragma unroll
  for (int m = 0; m < 4; m++)
#pragma unroll
    for (int n = 0; n < 4; n++) {
      int cl = wc * 64 + n * 16 + l15;
      int kv = kt * 128 + cl;
#pragma unroll
      for (int r = 0; r < 4; r++) {
        int rl = wr * 64 + m * 16 + l4 * 4 + r;
        int srow = qt * 128 + rl;
        float v = acc[m][n][r] * SCALE;
        if (kv > srow) v = -30000.f;      // f16-representable; exp -> 0
        outp[(size_t)rl * Wspan + kv] = f2h(v);
      }
    }
}

// ---- kernel 4: row softmax over f16 scores (8 elems/thread), write f16 P ----
__global__ __launch_bounds__(256) void softmax_row(const unsigned short* __restrict__ sc,
                                                   unsigned short* __restrict__ pb) {
  __shared__ float redm[4];
  __shared__ float reds[4];
  int srow = blockIdx.x;
  int b = srow >> 11, sl = srow & 2047;
  int qt = sl >> 7;
  int Wspan = (qt + 1) << 7;
  size_t rb = (size_t)b * P_ELEMS + (size_t)16384 * (qt * (qt + 1) / 2) + (size_t)(sl & 127) * Wspan;
  const u16x8* src = (const u16x8*)(sc + rb);
  int nv = Wspan >> 3;                       // <= 256
  int t = threadIdx.x, lane = t & 63, w = t >> 6;
  bool h0 = t < nv;
  float v[8];
  float mx = -1e30f;
  if (h0) {
    u16x8 raw = src[t];
#pragma unroll
    for (int j = 0; j < 8; j++) { v[j] = h2f(raw[j]); mx = fmaxf(mx, v[j]); }
  }
  for (int off = 1; off < 64; off <<= 1) mx = fmaxf(mx, __shfl_xor(mx, off, 64));
  if (lane == 0) redm[w] = mx;
  __syncthreads();
  mx = fmaxf(fmaxf(redm[0], redm[1]), fmaxf(redm[2], redm[3]));
  float s = 0.f;
  if (h0) {
#pragma unroll
    for (int j = 0; j < 8; j++) { v[j] = __expf(v[j] - mx); s += v[j]; }
  }
  for (int off = 1; off < 64; off <<= 1) s += __shfl_xor(s, off, 64);
  if (lane == 0) reds[w] = s;
  __syncthreads();
  s = reds[0] + reds[1] + reds[2] + reds[3];
  float inv = 1.f / s;
  if (h0) {
    u16x8 o;
#pragma unroll
    for (int j = 0; j < 8; j++) o[j] = f2h(v[j] * inv);
    *((u16x8*)(pb + rb) + t) = o;
  }
}

// ---- kernel 5: O = P Vt — paired tiles (qt=p and 15-p): 34 K-iters per block ----
__global__ __launch_bounds__(256) void pv_gemm(const unsigned short* __restrict__ pb,
                                               const unsigned short* __restrict__ vtp,
                                               float* __restrict__ outp) {
  __shared__ unsigned short lds[2][16384];
  int p = blockIdx.x;        // 0..7
  int n0 = blockIdx.y * 128;
  int b = blockIdx.z;
  int tid = threadIdx.x, lane = tid & 63, w = tid >> 6;
  int wr = w >> 1, wc = w & 1, l15 = lane & 15, l4 = lane >> 4;
  const unsigned short* gB = vtp + (size_t)b * 1024 * 2048 + (size_t)n0 * 2048;
#pragma unroll
  for (int which = 0; which < 2; which++) {
    int qt = which ? (15 - p) : p;
    int Wspan = (qt + 1) << 7;
    const unsigned short* gA = pb + (size_t)b * P_ELEMS + (size_t)16384 * (qt * (qt + 1) / 2);
    float* O = outp + ((size_t)b * 2048 + qt * 128) * 1024;
    f32x4 acc[4][4] = {};
    gemm_core(gA, gB, Wspan, 2048, &lds[0][0], &lds[1][0], 2 * (qt + 1),
              w, lane, wr, wc, l15, l4, acc);
#pragma unroll
    for (int m = 0; m < 4; m++)
#pragma unroll
      for (int n = 0; n < 4; n++) {
        int cl = n0 + wc * 64 + n * 16 + l15;
#pragma unroll
        for (int r = 0; r < 4; r++) {
          int rl = wr * 64 + m * 16 + l4 * 4 + r;
          O[(size_t)rl * 1024 + cl] = acc[m][n][r];
        }
      }
  }
}

extern "C" void kernel_launch(void* const* d_in, const int* in_sizes, int n_in,
                              void* d_out, int out_size, void* d_ws, size_t ws_size,
                              hipStream_t stream) {
  const float* x  = (const float*)d_in[0];
  const float* Wq = (const float*)d_in[1];
  const float* bq = (const float*)d_in[2];
  const float* Wk = (const float*)d_in[3];
  const float* bk = (const float*)d_in[4];
  const float* Wv = (const float*)d_in[5];
  const float* bv = (const float*)d_in[6];
  float* out = (float*)d_out;

  unsigned short* ws  = (unsigned short*)d_ws;
  unsigned short* wt  = ws;                          // 3,145,728 ushorts
  unsigned short* Qp  = ws + 3145728;                // 8,388,608
  unsigned short* Kp  = ws + 11534336;               // 8,388,608
  unsigned short* vtp = ws + 19922944;               // 8,388,608 (V^T [b][d][s])
  unsigned short* sc  = ws + 28311552;               // 4*P_ELEMS f16 scores
  unsigned short* pb  = ws + 37224448;               // 4*P_ELEMS f16 P
  unsigned short* xb  = (unsigned short*)d_out;      // x f16 scratch (overwritten by pv)

  cvt_fused<<<7168, 256, 0, stream>>>(x, Wq, Wk, Wv, xb, wt);
  qkv_gemm<<<dim3(64, 24), 256, 0, stream>>>(xb, wt, bq, bk, bv, Qp, Kp, vtp);
  qk_scores<<<dim3(136, 4), 256, 0, stream>>>(Qp, Kp, sc);
  softmax_row<<<8192, 256, 0, stream>>>(sc, pb);
  pv_gemm<<<dim3(8, 8, 4), 256, 0, stream>>>(pb, vtp, out);
}